// Round 1
// baseline (184.299 us; speedup 1.0000x reference)
//
#include <hip/hip_runtime.h>

#define D_IN 128
#define NH   16

// Fused prep: zero the output AND (block 0) collapse W0@W1@W2 -> w[128].
__global__ void prep_kernel(const float* __restrict__ W0,
                            const float* __restrict__ W1,
                            const float* __restrict__ W2,
                            float* __restrict__ w,
                            float* __restrict__ out, int m) {
    int i = blockIdx.x * blockDim.x + threadIdx.x;
    if (i < m) out[i] = 0.f;

    if (blockIdx.x == 0) {
        __shared__ float v1[NH];
        int t = threadIdx.x;
        if (t < NH) {
            float s = 0.f;
            #pragma unroll
            for (int k = 0; k < NH; ++k) s += W1[t * NH + k] * W2[k];
            v1[t] = s;
        }
        __syncthreads();
        if (t < D_IN) {
            float s = 0.f;
            #pragma unroll
            for (int j = 0; j < NH; ++j) s += W0[t * NH + j] * v1[j];
            w[t] = s;
        }
    }
}

// Main kernel: per half-wave dot(x[atom], w) -> LDS, then per-wave segmented
// scan over sorted structure ids -> one atomicAdd per run-tail.
__global__ __launch_bounds__(256) void predict_scatter_kernel(
        const float* __restrict__ x,
        const int*   __restrict__ sid,
        const float* __restrict__ w,
        float*       __restrict__ out,
        int n, int nTiles) {
    __shared__ float preds[256];

    const int lane  = threadIdx.x & 63;   // lane in wave
    const int hlane = threadIdx.x & 31;   // lane in half-wave
    const int hw    = threadIdx.x >> 5;   // half-wave id 0..7

    // Each lane holds 4 consecutive weights (whole half-wave covers 128).
    const float4 wv = reinterpret_cast<const float4*>(w)[hlane];

    for (int tile = blockIdx.x; tile < nTiles; tile += gridDim.x) {
        const long long tileBase = (long long)tile * 256;

        // ---- dot phase: half-wave hw handles atoms tileBase + hw*32 + step
        if (tileBase + 256 <= (long long)n) {
            #pragma unroll 4
            for (int step = 0; step < 32; ++step) {
                const long long atom = tileBase + hw * 32 + step;
                float4 xv = reinterpret_cast<const float4*>(x)[atom * 32 + hlane];
                float d = xv.x * wv.x + xv.y * wv.y + xv.z * wv.z + xv.w * wv.w;
                #pragma unroll
                for (int off = 16; off >= 1; off >>= 1)
                    d += __shfl_xor(d, off, 32);
                if (hlane == 0) preds[hw * 32 + step] = d;
            }
        } else {
            for (int step = 0; step < 32; ++step) {
                const long long atom = tileBase + hw * 32 + step;
                if (atom < (long long)n) {
                    float4 xv = reinterpret_cast<const float4*>(x)[atom * 32 + hlane];
                    float d = xv.x * wv.x + xv.y * wv.y + xv.z * wv.z + xv.w * wv.w;
                    #pragma unroll
                    for (int off = 16; off >= 1; off >>= 1)
                        d += __shfl_xor(d, off, 32);
                    if (hlane == 0) preds[hw * 32 + step] = d;
                }
            }
        }
        __syncthreads();

        // ---- scan + scatter phase: thread i owns tile atom i
        {
            const long long g = tileBase + threadIdx.x;
            float p = 0.f;
            int   s = -1;
            if (g < (long long)n) {
                p = preds[threadIdx.x];
                s = sid[g];
            }
            // segmented inclusive scan across the 64-lane wave
            #pragma unroll
            for (int off = 1; off < 64; off <<= 1) {
                float pv = __shfl_up(p, off, 64);
                int   sv = __shfl_up(s, off, 64);
                if (lane >= off && sv == s) p += pv;
            }
            int  sn   = __shfl_down(s, 1, 64);
            bool tail = (lane == 63) || (sn != s);
            if (tail && s >= 0) atomicAdd(&out[s], p);
        }
        __syncthreads();
    }
}

extern "C" void kernel_launch(void* const* d_in, const int* in_sizes, int n_in,
                              void* d_out, int out_size, void* d_ws, size_t ws_size,
                              hipStream_t stream) {
    const float* x   = (const float*)d_in[0];
    const float* W0  = (const float*)d_in[1];
    const float* W1  = (const float*)d_in[2];
    const float* W2  = (const float*)d_in[3];
    const int*   sid = (const int*)d_in[4];
    float*       out = (float*)d_out;
    float*       w   = (float*)d_ws;   // 128 floats of scratch

    const int n = in_sizes[0] / D_IN;  // N_ATOMS

    // prep: zero out[out_size] + compute w
    {
        int blocks = (out_size + 255) / 256;
        if (blocks < 1) blocks = 1;
        prep_kernel<<<blocks, 256, 0, stream>>>(W0, W1, W2, w, out, out_size);
    }

    // main
    {
        const int nTiles  = (n + 255) >> 8;
        int       nblocks = nTiles < 2048 ? nTiles : 2048;
        predict_scatter_kernel<<<nblocks, 256, 0, stream>>>(x, sid, w, out, n, nTiles);
    }
}

// Round 2
// 169.801 us; speedup vs baseline: 1.0854x; 1.0854x over previous
//
#include <hip/hip_runtime.h>

typedef float f32x2 __attribute__((ext_vector_type(2)));

#define D_IN 128
#define NH   16
#define APW  256   // atoms per wave-strip
#define BS   8     // atoms per load batch (double-buffered)

// Prep: zero out[] and (block 0) collapse W0@W1@W2 -> w[128].
__global__ void prep_kernel(const float* __restrict__ W0,
                            const float* __restrict__ W1,
                            const float* __restrict__ W2,
                            float* __restrict__ w,
                            float* __restrict__ out, int m) {
    int i = blockIdx.x * blockDim.x + threadIdx.x;
    if (i < m) out[i] = 0.f;
    if (blockIdx.x == 0) {
        __shared__ float v1[NH];
        int t = threadIdx.x;
        if (t < NH) {
            float s = 0.f;
            #pragma unroll
            for (int k = 0; k < NH; ++k) s += W1[t * NH + k] * W2[k];
            v1[t] = s;
        }
        __syncthreads();
        if (t < D_IN) {
            float s = 0.f;
            #pragma unroll
            for (int j = 0; j < NH; ++j) s += W0[t * NH + j] * v1[j];
            w[t] = s;
        }
    }
}

__device__ __forceinline__ void flush_seg(float r, int seg, float* __restrict__ out) {
    #pragma unroll
    for (int off = 32; off >= 1; off >>= 1) r += __shfl_xor(r, off, 64);
    if ((threadIdx.x & 63) == 0) atomicAdd(out + seg, r);
}

__global__ __launch_bounds__(256) void main_kernel(
        const float* __restrict__ x,
        const int*   __restrict__ sid,
        const float* __restrict__ w,
        float*       __restrict__ out,
        int n, int nStrips, int totalWaves) {
    const int lane   = threadIdx.x & 63;
    const int waveG  = __builtin_amdgcn_readfirstlane((blockIdx.x << 2) + (threadIdx.x >> 6));

    const f32x2* __restrict__ x2 = reinterpret_cast<const f32x2*>(x);
    const f32x2 wv = reinterpret_cast<const f32x2*>(w)[lane];

    for (int strip = waveG; strip < nStrips; strip += totalWaves) {
        const int base  = strip * APW;
        const int count = min(APW, n - base);
        const f32x2* __restrict__ xs = x2 + (long long)base * 64 + lane;

        int   cur = sid[base];   // scalar load (base is wave-uniform)
        float r   = 0.f;

        if (count == APW) {
            f32x2 A[BS], B[BS];
            #pragma unroll
            for (int s = 0; s < BS; ++s) A[s] = __builtin_nontemporal_load(&xs[s * 64]);

            const int NB = APW / BS;   // 32, even
            for (int ib = 0; ib < NB; ib += 2) {
                {   // prefetch batch ib+1 -> B
                    const f32x2* p = xs + (ib + 1) * BS * 64;
                    #pragma unroll
                    for (int s = 0; s < BS; ++s) B[s] = __builtin_nontemporal_load(&p[s * 64]);
                }
                {   // process A
                    const int off = base + ib * BS;
                    int slast = sid[off + BS - 1];
                    if (slast == cur) {
                        #pragma unroll
                        for (int s = 0; s < BS; ++s) r += A[s].x * wv.x + A[s].y * wv.y;
                    } else {
                        #pragma unroll
                        for (int s = 0; s < BS; ++s) {
                            int cs = sid[off + s];
                            if (cs != cur) { flush_seg(r, cur, out); r = 0.f; cur = cs; }
                            r += A[s].x * wv.x + A[s].y * wv.y;
                        }
                    }
                }
                if (ib + 2 < NB) {   // prefetch batch ib+2 -> A
                    const f32x2* p = xs + (ib + 2) * BS * 64;
                    #pragma unroll
                    for (int s = 0; s < BS; ++s) A[s] = __builtin_nontemporal_load(&p[s * 64]);
                }
                {   // process B
                    const int off = base + (ib + 1) * BS;
                    int slast = sid[off + BS - 1];
                    if (slast == cur) {
                        #pragma unroll
                        for (int s = 0; s < BS; ++s) r += B[s].x * wv.x + B[s].y * wv.y;
                    } else {
                        #pragma unroll
                        for (int s = 0; s < BS; ++s) {
                            int cs = sid[off + s];
                            if (cs != cur) { flush_seg(r, cur, out); r = 0.f; cur = cs; }
                            r += B[s].x * wv.x + B[s].y * wv.y;
                        }
                    }
                }
            }
        } else {
            // tail strip (at most one wave hits this): simple guarded loop
            for (int s = 0; s < count; ++s) {
                int cs = sid[base + s];
                if (cs != cur) { flush_seg(r, cur, out); r = 0.f; cur = cs; }
                f32x2 xv = xs[s * 64];
                r += xv.x * wv.x + xv.y * wv.y;
            }
        }
        flush_seg(r, cur, out);
    }
}

extern "C" void kernel_launch(void* const* d_in, const int* in_sizes, int n_in,
                              void* d_out, int out_size, void* d_ws, size_t ws_size,
                              hipStream_t stream) {
    const float* x   = (const float*)d_in[0];
    const float* W0  = (const float*)d_in[1];
    const float* W1  = (const float*)d_in[2];
    const float* W2  = (const float*)d_in[3];
    const int*   sid = (const int*)d_in[4];
    float*       out = (float*)d_out;
    float*       w   = (float*)d_ws;   // 128 floats of scratch

    const int n = in_sizes[0] / D_IN;  // N_ATOMS

    {   // prep: zero out[out_size] + compute w
        int blocks = (out_size + 255) / 256;
        if (blocks < 1) blocks = 1;
        prep_kernel<<<blocks, 256, 0, stream>>>(W0, W1, W2, w, out, out_size);
    }

    {   // main: one 256-atom strip per wave
        const int nStrips = (n + APW - 1) / APW;
        int nblocks = (nStrips + 3) / 4;
        if (nblocks > 2048) nblocks = 2048;
        const int totalWaves = nblocks * 4;
        main_kernel<<<nblocks, 256, 0, stream>>>(x, sid, w, out, n, nStrips, totalWaves);
    }
}